// Round 1
// baseline (586.843 us; speedup 1.0000x reference)
//
#include <hip/hip_runtime.h>
#include <hip/hip_bf16.h>

#define BSZ    2
#define LSEQ   4096
#define DMODEL 2048
#define DTR    128
#define DST    16
#define ODIM   160            // DTR + 2*DST
#define MROWS  (BSZ*LSEQ)     // 8192
#define CH     32             // chunks along L
#define TT     (LSEQ/CH)      // 128 steps per chunk
#define LOG2E  1.44269504088896340736f

typedef short  short8  __attribute__((ext_vector_type(8)));
typedef float  floatx4 __attribute__((ext_vector_type(4)));

__device__ __forceinline__ unsigned short f2bf(float f) {
    unsigned u = __float_as_uint(f);
    u += 0x7fffu + ((u >> 16) & 1u);      // round-to-nearest-even
    return (unsigned short)(u >> 16);
}
__device__ __forceinline__ float quantv(float x, float s, float inv_s) {
    float q = rintf(x * inv_s);
    q = fminf(fmaxf(q, -128.0f), 127.0f);
    return q * s;
}
__device__ __forceinline__ float softplusf_(float x) {
    return fmaxf(x, 0.0f) + log1pf(__expf(-fabsf(x)));
}
__device__ __forceinline__ float scale_from_bits(unsigned bits) {
    return fmaxf(__uint_as_float(bits) * (1.0f/127.0f), 1e-8f);
}

// ---------------------------------------------------------------- prep ------
#define PB_WX  160
#define PB_WDT 2048
#define PB_A   128
#define PB_D   1
#define PB_X   1024
#define PREP_BLOCKS (PB_WX + PB_WDT + PB_A + PB_D + PB_X)

__global__ __launch_bounds__(256) void k_prep(
    const float* __restrict__ x, const float* __restrict__ Wx,
    const float* __restrict__ Wdt, const float* __restrict__ A_log,
    const float* __restrict__ Dskip,
    unsigned short* __restrict__ Wxq, unsigned short* __restrict__ Wdtq,
    float* __restrict__ a2, float* __restrict__ Dq, unsigned* __restrict__ scales)
{
    int bid = blockIdx.x, tid = threadIdx.x;
    __shared__ float red[256];
    if (bid < PB_WX) {                       // Wx rows: per-channel quant -> bf16
        int base = bid * DMODEL;
        float m = 0.0f;
        for (int i = tid; i < DMODEL; i += 256) m = fmaxf(m, fabsf(Wx[base+i]));
        red[tid] = m; __syncthreads();
        for (int s2 = 128; s2 > 0; s2 >>= 1) { if (tid < s2) red[tid] = fmaxf(red[tid], red[tid+s2]); __syncthreads(); }
        float s = fmaxf(red[0]*(1.0f/127.0f), 1e-8f), inv = 1.0f/s;
        for (int i = tid; i < DMODEL; i += 256) Wxq[base+i] = f2bf(quantv(Wx[base+i], s, inv));
    } else if (bid < PB_WX + PB_WDT) {       // Wdt rows
        int row = bid - PB_WX, base = row*DTR;
        float m = (tid < DTR) ? fabsf(Wdt[base+tid]) : 0.0f;
        red[tid] = m; __syncthreads();
        for (int s2 = 128; s2 > 0; s2 >>= 1) { if (tid < s2) red[tid] = fmaxf(red[tid], red[tid+s2]); __syncthreads(); }
        float s = fmaxf(red[0]*(1.0f/127.0f), 1e-8f), inv = 1.0f/s;
        if (tid < DTR) Wdtq[base+tid] = f2bf(quantv(Wdt[base+tid], s, inv));
    } else if (bid < PB_WX + PB_WDT + PB_A) { // A_log rows (16 per block) -> a2 = -exp(q)*log2e
        int d = (bid - PB_WX - PB_WDT)*16 + (tid >> 4);
        int n = tid & 15;
        float v = A_log[d*DST + n];
        float m = fabsf(v);
        for (int off = 1; off < 16; off <<= 1) m = fmaxf(m, __shfl_xor(m, off, 16));
        float s = fmaxf(m*(1.0f/127.0f), 1e-8f);
        float q = quantv(v, s, 1.0f/s);
        a2[d*DST + n] = -expf(q) * LOG2E;
    } else if (bid < PB_WX + PB_WDT + PB_A + PB_D) {  // Dskip per-tensor quant
        float m = 0.0f;
        for (int i = tid; i < DMODEL; i += 256) m = fmaxf(m, fabsf(Dskip[i]));
        red[tid] = m; __syncthreads();
        for (int s2 = 128; s2 > 0; s2 >>= 1) { if (tid < s2) red[tid] = fmaxf(red[tid], red[tid+s2]); __syncthreads(); }
        float s = fmaxf(red[0]*(1.0f/127.0f), 1e-8f), inv = 1.0f/s;
        for (int i = tid; i < DMODEL; i += 256) Dq[i] = quantv(Dskip[i], s, inv);
    } else {                                  // global max|x|
        int xb = bid - (PB_WX + PB_WDT + PB_A + PB_D);
        const float4* xv = reinterpret_cast<const float4*>(x);
        int ntot = MROWS*DMODEL/4;
        float m = 0.0f;
        for (int i = xb*256 + tid; i < ntot; i += PB_X*256) {
            float4 v = xv[i];
            m = fmaxf(m, fmaxf(fmaxf(fabsf(v.x), fabsf(v.y)), fmaxf(fabsf(v.z), fabsf(v.w))));
        }
        for (int off = 32; off; off >>= 1) m = fmaxf(m, __shfl_xor(m, off, 64));
        if ((tid & 63) == 0) atomicMax(&scales[0], __float_as_uint(m));
    }
}

// ------------------------------------------------- GEMM1: x_dbl = x @ Wxq^T -
// one wave per block, 16 rows x 160 cols, K=2048 via 16x16x32 bf16 MFMA
__global__ __launch_bounds__(64) void k_mm1(
    const float* __restrict__ x, const unsigned short* __restrict__ Wxq,
    const float* __restrict__ prompt,
    float* __restrict__ xdbl, unsigned short* __restrict__ xdbl_bf,
    unsigned* __restrict__ scales)
{
    int lane = threadIdx.x;
    int mrow = lane & 15, quad = lane >> 4;
    int m0 = blockIdx.x * 16;
    floatx4 acc[10] = {};
    const float* arow = x + (size_t)(m0 + mrow)*DMODEL + quad*8;
    for (int kk = 0; kk < DMODEL; kk += 32) {
        const float4* ap = reinterpret_cast<const float4*>(arow + kk);
        float4 a0 = ap[0], a1 = ap[1];
        short8 af;
        af[0]=(short)f2bf(a0.x); af[1]=(short)f2bf(a0.y); af[2]=(short)f2bf(a0.z); af[3]=(short)f2bf(a0.w);
        af[4]=(short)f2bf(a1.x); af[5]=(short)f2bf(a1.y); af[6]=(short)f2bf(a1.z); af[7]=(short)f2bf(a1.w);
        #pragma unroll
        for (int j = 0; j < 10; ++j) {
            short8 bf = *reinterpret_cast<const short8*>(Wxq + (size_t)(j*16 + mrow)*DMODEL + kk + quad*8);
            acc[j] = __builtin_amdgcn_mfma_f32_16x16x32_bf16(af, bf, acc[j], 0, 0, 0);
        }
    }
    float bmax = 0.0f, cmax = 0.0f;
    #pragma unroll
    for (int j = 0; j < 10; ++j) {
        #pragma unroll
        for (int r = 0; r < 4; ++r) {
            int row = m0 + quad*4 + r;
            int col = j*16 + mrow;
            float v = acc[j][r];
            if (j == 9) { v += prompt[(size_t)row*DST + mrow]; cmax = fmaxf(cmax, fabsf(v)); }
            else if (j == 8) bmax = fmaxf(bmax, fabsf(v));
            xdbl[(size_t)row*ODIM + col] = v;
            if (j < 8) xdbl_bf[(size_t)row*DTR + col] = f2bf(v);
        }
    }
    for (int off = 32; off; off >>= 1) {
        bmax = fmaxf(bmax, __shfl_xor(bmax, off, 64));
        cmax = fmaxf(cmax, __shfl_xor(cmax, off, 64));
    }
    if (lane == 0) {
        atomicMax(&scales[1], __float_as_uint(bmax));
        atomicMax(&scales[2], __float_as_uint(cmax));
    }
}

// ------------------------------------- GEMM2: dts = xdbl[:, :128] @ Wdtq^T + bdt
__global__ __launch_bounds__(256) void k_mm2(
    const unsigned short* __restrict__ xdbl_bf, const unsigned short* __restrict__ Wdtq,
    const float* __restrict__ bdt, float* __restrict__ dts, unsigned* __restrict__ scales)
{
    int tid = threadIdx.x;
    int wave = tid >> 6, lane = tid & 63;
    int mrow = lane & 15, quad = lane >> 4;
    int mt = blockIdx.x >> 4, nt = blockIdx.x & 15;
    int m0 = mt*64 + wave*16, n0 = nt*128;
    floatx4 acc[8] = {};
    const unsigned short* ap = xdbl_bf + (size_t)(m0 + mrow)*DTR + quad*8;
    #pragma unroll
    for (int kk = 0; kk < DTR; kk += 32) {
        short8 af = *reinterpret_cast<const short8*>(ap + kk);
        #pragma unroll
        for (int j = 0; j < 8; ++j) {
            short8 bf = *reinterpret_cast<const short8*>(Wdtq + (size_t)(n0 + j*16 + mrow)*DTR + kk + quad*8);
            acc[j] = __builtin_amdgcn_mfma_f32_16x16x32_bf16(af, bf, acc[j], 0, 0, 0);
        }
    }
    float dmax = 0.0f;
    #pragma unroll
    for (int j = 0; j < 8; ++j) {
        int col = n0 + j*16 + mrow;
        float bv = bdt[col];
        #pragma unroll
        for (int r = 0; r < 4; ++r) {
            int row = m0 + quad*4 + r;
            float v = acc[j][r] + bv;
            dmax = fmaxf(dmax, fabsf(v));
            dts[(size_t)row*DMODEL + col] = v;
        }
    }
    for (int off = 32; off; off >>= 1) dmax = fmaxf(dmax, __shfl_xor(dmax, off, 64));
    if (lane == 0) atomicMax(&scales[3], __float_as_uint(dmax));
}

// ------------------------------------------- scan phase 1: chunk aggregates -
// block = (b, 256-d tile, chunk); thread owns one d, h[16] in registers
__global__ __launch_bounds__(256) void k_scan1(
    const float* __restrict__ dts, const float* __restrict__ x,
    const float* __restrict__ xdbl, const float* __restrict__ a2,
    const unsigned* __restrict__ scales,
    float* __restrict__ Aprod, float* __restrict__ hfin)
{
    int bid = blockIdx.x, tid = threadIdx.x;
    int b = bid >> 8, rem = bid & 255, dblk = rem >> 5, ch = rem & 31;
    int d0 = dblk*256, t0 = ch*TT;
    int d = d0 + tid;
    float s_u  = scale_from_bits(scales[0]), inv_su  = 1.0f/s_u;
    float s_B  = scale_from_bits(scales[1]), inv_sB  = 1.0f/s_B;
    float s_dt = scale_from_bits(scales[3]), inv_sdt = 1.0f/s_dt;
    float a2r[16];
    {
        const float4* ap = reinterpret_cast<const float4*>(a2 + (size_t)d*DST);
        float4 v0 = ap[0], v1 = ap[1], v2 = ap[2], v3 = ap[3];
        a2r[0]=v0.x; a2r[1]=v0.y; a2r[2]=v0.z; a2r[3]=v0.w;
        a2r[4]=v1.x; a2r[5]=v1.y; a2r[6]=v1.z; a2r[7]=v1.w;
        a2r[8]=v2.x; a2r[9]=v2.y; a2r[10]=v2.z; a2r[11]=v2.w;
        a2r[12]=v3.x; a2r[13]=v3.y; a2r[14]=v3.z; a2r[15]=v3.w;
    }
    float h[16];
    #pragma unroll
    for (int n = 0; n < 16; ++n) h[n] = 0.0f;
    float sdt = 0.0f;
    __shared__ float dt_p[16*256];
    __shared__ float dtu_p[16*256];
    __shared__ __align__(16) float Bq_p[16*16];
    for (int sub = 0; sub < TT/16; ++sub) {
        int tbase = t0 + sub*16;
        {   // stage quantized B tile (16 t x 16 n)
            int tb = tid >> 4, n = tid & 15;
            float bv = xdbl[(size_t)(b*LSEQ + tbase + tb)*ODIM + DTR + n];
            Bq_p[tb*16 + n] = quantv(bv, s_B, inv_sB);
        }
        for (int r = 0; r < 16; ++r) {   // stage dt (softplussed) and dt*u_q
            size_t idx = (size_t)(b*LSEQ + tbase + r)*DMODEL + d;
            float dtq = quantv(dts[idx], s_dt, inv_sdt);
            float dtv = softplusf_(dtq);
            float uq  = quantv(x[idx], s_u, inv_su);
            dt_p[r*256 + tid]  = dtv;
            dtu_p[r*256 + tid] = dtv * uq;
        }
        __syncthreads();
        for (int r = 0; r < 16; ++r) {
            float dtv = dt_p[r*256 + tid];
            float dtu = dtu_p[r*256 + tid];
            sdt += dtv;
            const float4* bq4 = reinterpret_cast<const float4*>(&Bq_p[r*16]);
            float4 b0 = bq4[0], b1 = bq4[1], b2 = bq4[2], b3 = bq4[3];
            float bq[16] = { b0.x,b0.y,b0.z,b0.w, b1.x,b1.y,b1.z,b1.w,
                             b2.x,b2.y,b2.z,b2.w, b3.x,b3.y,b3.z,b3.w };
            #pragma unroll
            for (int n = 0; n < 16; ++n) {
                float dA = __builtin_amdgcn_exp2f(a2r[n]*dtv);
                h[n] = fmaf(dA, h[n], dtu*bq[n]);
            }
        }
        __syncthreads();
    }
    size_t ob = ((size_t)((b*CH + ch)*DMODEL + d))*DST;
    #pragma unroll
    for (int i = 0; i < 4; ++i) {
        float4 av = make_float4(__builtin_amdgcn_exp2f(a2r[4*i+0]*sdt),
                                __builtin_amdgcn_exp2f(a2r[4*i+1]*sdt),
                                __builtin_amdgcn_exp2f(a2r[4*i+2]*sdt),
                                __builtin_amdgcn_exp2f(a2r[4*i+3]*sdt));
        float4 hv = make_float4(h[4*i+0], h[4*i+1], h[4*i+2], h[4*i+3]);
        *reinterpret_cast<float4*>(Aprod + ob + 4*i) = av;
        *reinterpret_cast<float4*>(hfin  + ob + 4*i) = hv;
    }
}

// ------------------------- scan phase 2: across-chunk recurrence (in-place) -
__global__ __launch_bounds__(256) void k_mid(
    float* __restrict__ Aprod, const float* __restrict__ hfin)
{
    int f = blockIdx.x*256 + threadIdx.x;      // 65536 = B*DMODEL*DST
    int b = f >> 15, dn = f & 32767;
    size_t base = (size_t)b*CH*32768 + dn;
    float h = 0.0f;
    for (int ch = 0; ch < CH; ++ch) {
        size_t o = base + (size_t)ch*32768;
        float a = Aprod[o], hf = hfin[o];
        Aprod[o] = h;                          // exclusive prefix -> h_init
        h = fmaf(a, h, hf);
    }
}

// --------------------- scan phase 3: replay with h_init, emit y + u_q*D_q ---
__global__ __launch_bounds__(256) void k_scan3(
    float* __restrict__ io /* dts in, y out (same layout) */,
    const float* __restrict__ x, const float* __restrict__ xdbl,
    const float* __restrict__ a2, const float* __restrict__ Dq,
    const unsigned* __restrict__ scales, const float* __restrict__ hinit)
{
    int bid = blockIdx.x, tid = threadIdx.x;
    int b = bid >> 8, rem = bid & 255, dblk = rem >> 5, ch = rem & 31;
    int d0 = dblk*256, t0 = ch*TT;
    int d = d0 + tid;
    float s_u  = scale_from_bits(scales[0]), inv_su  = 1.0f/s_u;
    float s_B  = scale_from_bits(scales[1]), inv_sB  = 1.0f/s_B;
    float s_C  = scale_from_bits(scales[2]), inv_sC  = 1.0f/s_C;
    float s_dt = scale_from_bits(scales[3]), inv_sdt = 1.0f/s_dt;
    float dqd = Dq[d];
    float a2r[16];
    {
        const float4* ap = reinterpret_cast<const float4*>(a2 + (size_t)d*DST);
        float4 v0 = ap[0], v1 = ap[1], v2 = ap[2], v3 = ap[3];
        a2r[0]=v0.x; a2r[1]=v0.y; a2r[2]=v0.z; a2r[3]=v0.w;
        a2r[4]=v1.x; a2r[5]=v1.y; a2r[6]=v1.z; a2r[7]=v1.w;
        a2r[8]=v2.x; a2r[9]=v2.y; a2r[10]=v2.z; a2r[11]=v2.w;
        a2r[12]=v3.x; a2r[13]=v3.y; a2r[14]=v3.z; a2r[15]=v3.w;
    }
    size_t ob = ((size_t)((b*CH + ch)*DMODEL + d))*DST;
    float h[16];
    #pragma unroll
    for (int i = 0; i < 4; ++i) {
        float4 hv = *reinterpret_cast<const float4*>(hinit + ob + 4*i);
        h[4*i+0]=hv.x; h[4*i+1]=hv.y; h[4*i+2]=hv.z; h[4*i+3]=hv.w;
    }
    __shared__ float dt_p[16*256];
    __shared__ float dtu_p[16*256];
    __shared__ float skip_p[16*256];
    __shared__ __align__(16) float Bq_p[16*16];
    __shared__ __align__(16) float Cq_p[16*16];
    for (int sub = 0; sub < TT/16; ++sub) {
        int tbase = t0 + sub*16;
        {
            int tb = tid >> 4, n = tid & 15;
            size_t pidx = (size_t)(b*LSEQ + tbase + tb)*ODIM;
            Bq_p[tb*16 + n] = quantv(xdbl[pidx + DTR + n],       s_B, inv_sB);
            Cq_p[tb*16 + n] = quantv(xdbl[pidx + DTR + DST + n], s_C, inv_sC);
        }
        for (int r = 0; r < 16; ++r) {
            size_t idx = (size_t)(b*LSEQ + tbase + r)*DMODEL + d;
            float dtq = quantv(io[idx], s_dt, inv_sdt);
            float dtv = softplusf_(dtq);
            float uq  = quantv(x[idx], s_u, inv_su);
            dt_p[r*256 + tid]   = dtv;
            dtu_p[r*256 + tid]  = dtv * uq;
            skip_p[r*256 + tid] = uq * dqd;
        }
        __syncthreads();
        for (int r = 0; r < 16; ++r) {
            float dtv = dt_p[r*256 + tid];
            float dtu = dtu_p[r*256 + tid];
            const float4* bq4 = reinterpret_cast<const float4*>(&Bq_p[r*16]);
            const float4* cq4 = reinterpret_cast<const float4*>(&Cq_p[r*16]);
            float4 b0 = bq4[0], b1 = bq4[1], b2 = bq4[2], b3 = bq4[3];
            float4 c0 = cq4[0], c1 = cq4[1], c2 = cq4[2], c3 = cq4[3];
            float bq[16] = { b0.x,b0.y,b0.z,b0.w, b1.x,b1.y,b1.z,b1.w,
                             b2.x,b2.y,b2.z,b2.w, b3.x,b3.y,b3.z,b3.w };
            float cq[16] = { c0.x,c0.y,c0.z,c0.w, c1.x,c1.y,c1.z,c1.w,
                             c2.x,c2.y,c2.z,c2.w, c3.x,c3.y,c3.z,c3.w };
            float y = 0.0f;
            #pragma unroll
            for (int n = 0; n < 16; ++n) {
                float dA = __builtin_amdgcn_exp2f(a2r[n]*dtv);
                h[n] = fmaf(dA, h[n], dtu*bq[n]);
                y = fmaf(h[n], cq[n], y);
            }
            size_t idx = (size_t)(b*LSEQ + tbase + r)*DMODEL + d;
            io[idx] = y + skip_p[r*256 + tid];
        }
        __syncthreads();
    }
}

// ---------------------------------------------------------------------------
extern "C" void kernel_launch(void* const* d_in, const int* in_sizes, int n_in,
                              void* d_out, int out_size, void* d_ws, size_t ws_size,
                              hipStream_t stream)
{
    const float* x      = (const float*)d_in[0];
    const float* prompt = (const float*)d_in[1];
    const float* Wx     = (const float*)d_in[2];
    const float* Wdt    = (const float*)d_in[3];
    const float* bdt    = (const float*)d_in[4];
    const float* A_log  = (const float*)d_in[5];
    const float* Dskip  = (const float*)d_in[6];
    float* out = (float*)d_out;                  // also holds dts between mm2 and scan3
    char* ws = (char*)d_ws;
    size_t off = 0;
    unsigned* scales       = (unsigned*)(ws + off);        off += 256;
    unsigned short* Wxq    = (unsigned short*)(ws + off);  off += (size_t)ODIM*DMODEL*2;
    unsigned short* Wdtq   = (unsigned short*)(ws + off);  off += (size_t)DMODEL*DTR*2;
    float* a2              = (float*)(ws + off);           off += (size_t)DMODEL*DST*4;
    float* Dq              = (float*)(ws + off);           off += (size_t)DMODEL*4;
    float* xdbl            = (float*)(ws + off);           off += (size_t)MROWS*ODIM*4;
    unsigned short* xdblbf = (unsigned short*)(ws + off);  off += (size_t)MROWS*DTR*2;
    float* Aprod           = (float*)(ws + off);           off += (size_t)BSZ*CH*DMODEL*DST*4;
    float* hfin            = (float*)(ws + off);           off += (size_t)BSZ*CH*DMODEL*DST*4;

    hipMemsetAsync(scales, 0, 256, stream);
    hipLaunchKernelGGL(k_prep, dim3(PREP_BLOCKS), dim3(256), 0, stream,
                       x, Wx, Wdt, A_log, Dskip, Wxq, Wdtq, a2, Dq, scales);
    hipLaunchKernelGGL(k_mm1, dim3(MROWS/16), dim3(64), 0, stream,
                       x, Wxq, prompt, xdbl, xdblbf, scales);
    hipLaunchKernelGGL(k_mm2, dim3((MROWS/64)*(DMODEL/128)), dim3(256), 0, stream,
                       xdblbf, Wdtq, bdt, out, scales);
    hipLaunchKernelGGL(k_scan1, dim3(BSZ*8*CH), dim3(256), 0, stream,
                       out, x, xdbl, a2, scales, Aprod, hfin);
    hipLaunchKernelGGL(k_mid, dim3(BSZ*DMODEL*DST/256), dim3(256), 0, stream,
                       Aprod, hfin);
    hipLaunchKernelGGL(k_scan3, dim3(BSZ*8*CH), dim3(256), 0, stream,
                       out, x, xdbl, a2, Dq, scales, Aprod);
}

// Round 2
// 541.622 us; speedup vs baseline: 1.0835x; 1.0835x over previous
//
#include <hip/hip_runtime.h>
#include <hip/hip_bf16.h>

#define BSZ    2
#define LSEQ   4096
#define DMODEL 2048
#define DTR    128
#define DST    16
#define ODIM   160            // DTR + 2*DST
#define MROWS  (BSZ*LSEQ)     // 8192
#define CH     64             // chunks along L
#define TT     (LSEQ/CH)      // 64 steps per chunk
#define LOG2E  1.44269504088896340736f
#define LN2    0.69314718055994530942f

typedef short  short8  __attribute__((ext_vector_type(8)));
typedef float  floatx4 __attribute__((ext_vector_type(4)));

__device__ __forceinline__ unsigned short f2bf(float f) {
    unsigned u = __float_as_uint(f);
    u += 0x7fffu + ((u >> 16) & 1u);      // round-to-nearest-even
    return (unsigned short)(u >> 16);
}
__device__ __forceinline__ float quantv(float x, float s, float inv_s) {
    float q = rintf(x * inv_s);
    q = fminf(fmaxf(q, -128.0f), 127.0f);
    return q * s;
}
// softplus(x) = max(x,0) + log(1 + exp(-|x|)) via HW exp2/log2 (~5 instr)
__device__ __forceinline__ float softplus_fast(float v) {
    float t = __builtin_amdgcn_exp2f(-fabsf(v) * LOG2E);
    return fmaxf(v, 0.0f) + LN2 * __log2f(1.0f + t);
}
__device__ __forceinline__ float scale_from_bits(unsigned bits) {
    return fmaxf(__uint_as_float(bits) * (1.0f/127.0f), 1e-8f);
}

// ---------------------------------------------------------------- prep ------
// weights only (x-max fused into mm1)
#define PB_WX  160
#define PB_WDT 512      // 4 Wdt rows per block, one wave each
#define PB_A   128      // 16 d-rows per block
#define PB_D   1
#define PREP_BLOCKS (PB_WX + PB_WDT + PB_A + PB_D)

__global__ __launch_bounds__(256) void k_prep(
    const float* __restrict__ Wx, const float* __restrict__ Wdt,
    const float* __restrict__ A_log, const float* __restrict__ Dskip,
    unsigned short* __restrict__ Wxq, unsigned short* __restrict__ Wdtq,
    float* __restrict__ a2, float* __restrict__ Dq)
{
    int bid = blockIdx.x, tid = threadIdx.x;
    __shared__ float red[256];
    if (bid < PB_WX) {                       // Wx row: per-channel quant -> bf16
        int base = bid * DMODEL;
        float m = 0.0f;
        for (int i = tid; i < DMODEL; i += 256) m = fmaxf(m, fabsf(Wx[base+i]));
        red[tid] = m; __syncthreads();
        for (int s2 = 128; s2 > 0; s2 >>= 1) { if (tid < s2) red[tid] = fmaxf(red[tid], red[tid+s2]); __syncthreads(); }
        float s = fmaxf(red[0]*(1.0f/127.0f), 1e-8f), inv = 1.0f/s;
        for (int i = tid; i < DMODEL; i += 256) Wxq[base+i] = f2bf(quantv(Wx[base+i], s, inv));
    } else if (bid < PB_WX + PB_WDT) {       // Wdt: wave per row, 2 elems/lane
        int wave = tid >> 6, lane = tid & 63;
        int row = (bid - PB_WX)*4 + wave, base = row*DTR + lane*2;
        float2 v = *reinterpret_cast<const float2*>(Wdt + base);
        float m = fmaxf(fabsf(v.x), fabsf(v.y));
        for (int off = 32; off; off >>= 1) m = fmaxf(m, __shfl_xor(m, off, 64));
        float s = fmaxf(m*(1.0f/127.0f), 1e-8f), inv = 1.0f/s;
        ushort2 o; o.x = f2bf(quantv(v.x, s, inv)); o.y = f2bf(quantv(v.y, s, inv));
        *reinterpret_cast<ushort2*>(Wdtq + base) = o;
    } else if (bid < PB_WX + PB_WDT + PB_A) { // A_log -> a2 = -exp(q)*log2e
        int d = (bid - PB_WX - PB_WDT)*16 + (tid >> 4);
        int n = tid & 15;
        float v = A_log[d*DST + n];
        float m = fabsf(v);
        for (int off = 1; off < 16; off <<= 1) m = fmaxf(m, __shfl_xor(m, off, 16));
        float s = fmaxf(m*(1.0f/127.0f), 1e-8f);
        float q = quantv(v, s, 1.0f/s);
        a2[d*DST + n] = -expf(q) * LOG2E;
    } else {                                  // Dskip per-tensor quant
        float m = 0.0f;
        for (int i = tid; i < DMODEL; i += 256) m = fmaxf(m, fabsf(Dskip[i]));
        red[tid] = m; __syncthreads();
        for (int s2 = 128; s2 > 0; s2 >>= 1) { if (tid < s2) red[tid] = fmaxf(red[tid], red[tid+s2]); __syncthreads(); }
        float s = fmaxf(red[0]*(1.0f/127.0f), 1e-8f), inv = 1.0f/s;
        for (int i = tid; i < DMODEL; i += 256) Dq[i] = quantv(Dskip[i], s, inv);
    }
}

// ---------------------- GEMM1 (K-split x4): partial x_dbl + global max|x| ---
__global__ __launch_bounds__(64) void k_mm1(
    const float* __restrict__ x, const unsigned short* __restrict__ Wxq,
    float* __restrict__ part, unsigned* __restrict__ scales)
{
    int lane = threadIdx.x;
    int mrow = lane & 15, quad = lane >> 4;
    int blk = blockIdx.x;
    int kc = blk & 3;                // K chunk (512 wide)
    int m0 = (blk >> 2) * 16;
    int k0 = kc * 512;
    floatx4 acc[10] = {};
    float xmax = 0.0f;
    const float* arow = x + (size_t)(m0 + mrow)*DMODEL + k0 + quad*8;
    for (int kk = 0; kk < 512; kk += 32) {
        const float4* ap = reinterpret_cast<const float4*>(arow + kk);
        float4 a0 = ap[0], a1 = ap[1];
        xmax = fmaxf(xmax, fmaxf(fmaxf(fabsf(a0.x), fabsf(a0.y)), fmaxf(fabsf(a0.z), fabsf(a0.w))));
        xmax = fmaxf(xmax, fmaxf(fmaxf(fabsf(a1.x), fabsf(a1.y)), fmaxf(fabsf(a1.z), fabsf(a1.w))));
        short8 af;
        af[0]=(short)f2bf(a0.x); af[1]=(short)f2bf(a0.y); af[2]=(short)f2bf(a0.z); af[3]=(short)f2bf(a0.w);
        af[4]=(short)f2bf(a1.x); af[5]=(short)f2bf(a1.y); af[6]=(short)f2bf(a1.z); af[7]=(short)f2bf(a1.w);
        #pragma unroll
        for (int j = 0; j < 10; ++j) {
            short8 bf = *reinterpret_cast<const short8*>(Wxq + (size_t)(j*16 + mrow)*DMODEL + k0 + kk + quad*8);
            acc[j] = __builtin_amdgcn_mfma_f32_16x16x32_bf16(af, bf, acc[j], 0, 0, 0);
        }
    }
    #pragma unroll
    for (int j = 0; j < 10; ++j) {
        #pragma unroll
        for (int r = 0; r < 4; ++r) {
            int row = m0 + quad*4 + r;
            int col = j*16 + mrow;
            part[((size_t)kc*MROWS + row)*ODIM + col] = acc[j][r];
        }
    }
    for (int off = 32; off; off >>= 1) xmax = fmaxf(xmax, __shfl_xor(xmax, off, 64));
    if (lane == 0) atomicMax(&scales[0], __float_as_uint(xmax));
}

// ------- reduce partials -> bf16 dt-cols + compact B/C cols + B/C maxes -----
__global__ __launch_bounds__(256) void k_red1(
    const float* __restrict__ part, const float* __restrict__ prompt,
    unsigned short* __restrict__ xdblbf, float* __restrict__ xbc,
    unsigned* __restrict__ scales)
{
    const int S = MROWS*ODIM;
    int tid = threadIdx.x;
    int base = blockIdx.x * 2560;            // 16 rows x 160 cols per block
    float bmax = 0.0f, cmax = 0.0f;
    #pragma unroll
    for (int j = 0; j < 10; ++j) {
        int e = base + j*256 + tid;
        float v = part[e] + part[e + S] + part[e + 2*S] + part[e + 3*S];
        int row = e / ODIM, col = e - row*ODIM;
        if (col < DTR) {
            xdblbf[(size_t)row*DTR + col] = f2bf(v);
        } else if (col < DTR + DST) {
            bmax = fmaxf(bmax, fabsf(v));
            xbc[(size_t)row*32 + (col - DTR)] = v;
        } else {
            v += prompt[(size_t)row*DST + (col - DTR - DST)];
            cmax = fmaxf(cmax, fabsf(v));
            xbc[(size_t)row*32 + 16 + (col - DTR - DST)] = v;
        }
    }
    __shared__ float redB[256], redC[256];
    redB[tid] = bmax; redC[tid] = cmax; __syncthreads();
    for (int s2 = 128; s2 > 0; s2 >>= 1) {
        if (tid < s2) { redB[tid] = fmaxf(redB[tid], redB[tid+s2]); redC[tid] = fmaxf(redC[tid], redC[tid+s2]); }
        __syncthreads();
    }
    if (tid == 0) {
        atomicMax(&scales[1], __float_as_uint(redB[0]));
        atomicMax(&scales[2], __float_as_uint(redC[0]));
    }
}

// ------------------------------------- GEMM2: dts = xdblbf @ Wdtq^T + bdt ---
__global__ __launch_bounds__(256) void k_mm2(
    const unsigned short* __restrict__ xdbl_bf, const unsigned short* __restrict__ Wdtq,
    const float* __restrict__ bdt, float* __restrict__ dts, unsigned* __restrict__ scales)
{
    int tid = threadIdx.x;
    int wave = tid >> 6, lane = tid & 63;
    int mrow = lane & 15, quad = lane >> 4;
    int mt = blockIdx.x >> 4, nt = blockIdx.x & 15;
    int m0 = mt*64 + wave*16, n0 = nt*128;
    floatx4 acc[8] = {};
    const unsigned short* ap = xdbl_bf + (size_t)(m0 + mrow)*DTR + quad*8;
    #pragma unroll
    for (int kk = 0; kk < DTR; kk += 32) {
        short8 af = *reinterpret_cast<const short8*>(ap + kk);
        #pragma unroll
        for (int j = 0; j < 8; ++j) {
            short8 bf = *reinterpret_cast<const short8*>(Wdtq + (size_t)(n0 + j*16 + mrow)*DTR + kk + quad*8);
            acc[j] = __builtin_amdgcn_mfma_f32_16x16x32_bf16(af, bf, acc[j], 0, 0, 0);
        }
    }
    float dmax = 0.0f;
    #pragma unroll
    for (int j = 0; j < 8; ++j) {
        int col = n0 + j*16 + mrow;
        float bv = bdt[col];
        #pragma unroll
        for (int r = 0; r < 4; ++r) {
            int row = m0 + quad*4 + r;
            float v = acc[j][r] + bv;
            dmax = fmaxf(dmax, fabsf(v));
            dts[(size_t)row*DMODEL + col] = v;
        }
    }
    for (int off = 32; off; off >>= 1) dmax = fmaxf(dmax, __shfl_xor(dmax, off, 64));
    if (lane == 0) atomicMax(&scales[3], __float_as_uint(dmax));
}

// ------------------------------------------- scan phase 1: chunk aggregates -
// grid = BSZ*8*CH blocks of 256; thread owns one d, h[16] in regs, 2KB LDS
__global__ __launch_bounds__(256, 4) void k_scan1(
    const float* __restrict__ dts, const float* __restrict__ x,
    const float* __restrict__ xbc, const float* __restrict__ a2,
    const unsigned* __restrict__ scales,
    float* __restrict__ Aprod, float* __restrict__ hfin)
{
    int bid = blockIdx.x, tid = threadIdx.x;
    int b = bid >> 9, rem = bid & 511, dblk = rem >> 6, ch = rem & 63;
    int d = dblk*256 + tid, t0 = ch*TT;
    float s_u  = scale_from_bits(scales[0]), inv_su  = 1.0f/s_u;
    float s_B  = scale_from_bits(scales[1]), inv_sB  = 1.0f/s_B;
    float s_dt = scale_from_bits(scales[3]), inv_sdt = 1.0f/s_dt;
    float a2r[16];
    {
        const float4* ap = reinterpret_cast<const float4*>(a2 + (size_t)d*DST);
        float4 v0 = ap[0], v1 = ap[1], v2 = ap[2], v3 = ap[3];
        a2r[0]=v0.x; a2r[1]=v0.y; a2r[2]=v0.z; a2r[3]=v0.w;
        a2r[4]=v1.x; a2r[5]=v1.y; a2r[6]=v1.z; a2r[7]=v1.w;
        a2r[8]=v2.x; a2r[9]=v2.y; a2r[10]=v2.z; a2r[11]=v2.w;
        a2r[12]=v3.x; a2r[13]=v3.y; a2r[14]=v3.z; a2r[15]=v3.w;
    }
    float h[16];
    #pragma unroll
    for (int n = 0; n < 16; ++n) h[n] = 0.0f;
    float sdt = 0.0f;
    __shared__ __align__(16) float Bq_p[16*16];
    for (int sub = 0; sub < TT/16; ++sub) {
        int tbase = t0 + sub*16;
        {   // stage quantized B tile (16 t x 16 n)
            int tb = tid >> 4, n = tid & 15;
            float bv = xbc[(size_t)(b*LSEQ + tbase + tb)*32 + n];
            Bq_p[tb*16 + n] = quantv(bv, s_B, inv_sB);
        }
        float dtr[16], ur[16];
        const float* pD = dts + (size_t)(b*LSEQ + tbase)*DMODEL + d;
        const float* pX = x   + (size_t)(b*LSEQ + tbase)*DMODEL + d;
        #pragma unroll
        for (int r = 0; r < 16; ++r) { dtr[r] = pD[(size_t)r*DMODEL]; ur[r] = pX[(size_t)r*DMODEL]; }
        __syncthreads();
        #pragma unroll
        for (int r = 0; r < 16; ++r) {
            float dtq = quantv(dtr[r], s_dt, inv_sdt);
            float dtv = softplus_fast(dtq);
            float uq  = quantv(ur[r], s_u, inv_su);
            float dtu = dtv * uq;
            sdt += dtv;
            const float4* bq4 = reinterpret_cast<const float4*>(&Bq_p[r*16]);
            float4 b0 = bq4[0], b1 = bq4[1], b2 = bq4[2], b3 = bq4[3];
            float bq[16] = { b0.x,b0.y,b0.z,b0.w, b1.x,b1.y,b1.z,b1.w,
                             b2.x,b2.y,b2.z,b2.w, b3.x,b3.y,b3.z,b3.w };
            #pragma unroll
            for (int n = 0; n < 16; ++n) {
                float dA = __builtin_amdgcn_exp2f(a2r[n]*dtv);
                h[n] = fmaf(dA, h[n], dtu*bq[n]);
            }
        }
        __syncthreads();
    }
    size_t ob = ((size_t)((b*CH + ch)*DMODEL + d))*DST;
    #pragma unroll
    for (int i = 0; i < 4; ++i) {
        float4 av = make_float4(__builtin_amdgcn_exp2f(a2r[4*i+0]*sdt),
                                __builtin_amdgcn_exp2f(a2r[4*i+1]*sdt),
                                __builtin_amdgcn_exp2f(a2r[4*i+2]*sdt),
                                __builtin_amdgcn_exp2f(a2r[4*i+3]*sdt));
        float4 hv = make_float4(h[4*i+0], h[4*i+1], h[4*i+2], h[4*i+3]);
        *reinterpret_cast<float4*>(Aprod + ob + 4*i) = av;
        *reinterpret_cast<float4*>(hfin  + ob + 4*i) = hv;
    }
}

// ------------------------- scan phase 2: across-chunk recurrence (in-place) -
__global__ __launch_bounds__(256) void k_mid(
    float* __restrict__ Aprod, const float* __restrict__ hfin)
{
    int f = blockIdx.x*256 + threadIdx.x;      // 65536 = B*DMODEL*DST
    int b = f >> 15, dn = f & 32767;
    size_t base = (size_t)b*CH*32768 + dn;
    float h = 0.0f;
    #pragma unroll 4
    for (int ch = 0; ch < CH; ++ch) {
        size_t o = base + (size_t)ch*32768;
        float a = Aprod[o], hf = hfin[o];
        Aprod[o] = h;                          // exclusive prefix -> h_init
        h = fmaf(a, h, hf);
    }
}

// --------------------- scan phase 3: replay with h_init, emit y + u_q*D_q ---
__global__ __launch_bounds__(256, 4) void k_scan3(
    float* __restrict__ io /* dts in, y out */,
    const float* __restrict__ x, const float* __restrict__ xbc,
    const float* __restrict__ a2, const float* __restrict__ Dq,
    const unsigned* __restrict__ scales, const float* __restrict__ hinit)
{
    int bid = blockIdx.x, tid = threadIdx.x;
    int b = bid >> 9, rem = bid & 511, dblk = rem >> 6, ch = rem & 63;
    int d = dblk*256 + tid, t0 = ch*TT;
    float s_u  = scale_from_bits(scales[0]), inv_su  = 1.0f/s_u;
    float s_B  = scale_from_bits(scales[1]), inv_sB  = 1.0f/s_B;
    float s_C  = scale_from_bits(scales[2]), inv_sC  = 1.0f/s_C;
    float s_dt = scale_from_bits(scales[3]), inv_sdt = 1.0f/s_dt;
    float dqd = Dq[d];
    float a2r[16];
    {
        const float4* ap = reinterpret_cast<const float4*>(a2 + (size_t)d*DST);
        float4 v0 = ap[0], v1 = ap[1], v2 = ap[2], v3 = ap[3];
        a2r[0]=v0.x; a2r[1]=v0.y; a2r[2]=v0.z; a2r[3]=v0.w;
        a2r[4]=v1.x; a2r[5]=v1.y; a2r[6]=v1.z; a2r[7]=v1.w;
        a2r[8]=v2.x; a2r[9]=v2.y; a2r[10]=v2.z; a2r[11]=v2.w;
        a2r[12]=v3.x; a2r[13]=v3.y; a2r[14]=v3.z; a2r[15]=v3.w;
    }
    size_t ob = ((size_t)((b*CH + ch)*DMODEL + d))*DST;
    float h[16];
    #pragma unroll
    for (int i = 0; i < 4; ++i) {
        float4 hv = *reinterpret_cast<const float4*>(hinit + ob + 4*i);
        h[4*i+0]=hv.x; h[4*i+1]=hv.y; h[4*i+2]=hv.z; h[4*i+3]=hv.w;
    }
    __shared__ __align__(16) float Bq_p[16*16];
    __shared__ __align__(16) float Cq_p[16*16];
    for (int sub = 0; sub < TT/16; ++sub) {
        int tbase = t0 + sub*16;
        {
            int tb = tid >> 4, n = tid & 15;
            size_t pidx = (size_t)(b*LSEQ + tbase + tb)*32;
            Bq_p[tb*16 + n] = quantv(xbc[pidx + n],      s_B, inv_sB);
            Cq_p[tb*16 + n] = quantv(xbc[pidx + 16 + n], s_C, inv_sC);
        }
        float dtr[16], ur[16];
        float* pD = io + (size_t)(b*LSEQ + tbase)*DMODEL + d;
        const float* pX = x + (size_t)(b*LSEQ + tbase)*DMODEL + d;
        #pragma unroll
        for (int r = 0; r < 16; ++r) { dtr[r] = pD[(size_t)r*DMODEL]; ur[r] = pX[(size_t)r*DMODEL]; }
        __syncthreads();
        #pragma unroll
        for (int r = 0; r < 16; ++r) {
            float dtq = quantv(dtr[r], s_dt, inv_sdt);
            float dtv = softplus_fast(dtq);
            float uq  = quantv(ur[r], s_u, inv_su);
            float dtu = dtv * uq;
            const float4* bq4 = reinterpret_cast<const float4*>(&Bq_p[r*16]);
            const float4* cq4 = reinterpret_cast<const float4*>(&Cq_p[r*16]);
            float4 b0 = bq4[0], b1 = bq4[1], b2 = bq4[2], b3 = bq4[3];
            float4 c0 = cq4[0], c1 = cq4[1], c2 = cq4[2], c3 = cq4[3];
            float bq[16] = { b0.x,b0.y,b0.z,b0.w, b1.x,b1.y,b1.z,b1.w,
                             b2.x,b2.y,b2.z,b2.w, b3.x,b3.y,b3.z,b3.w };
            float cq[16] = { c0.x,c0.y,c0.z,c0.w, c1.x,c1.y,c1.z,c1.w,
                             c2.x,c2.y,c2.z,c2.w, c3.x,c3.y,c3.z,c3.w };
            float y = 0.0f;
            #pragma unroll
            for (int n = 0; n < 16; ++n) {
                float dA = __builtin_amdgcn_exp2f(a2r[n]*dtv);
                h[n] = fmaf(dA, h[n], dtu*bq[n]);
                y = fmaf(h[n], cq[n], y);
            }
            pD[(size_t)r*DMODEL] = y + uq * dqd;
        }
        __syncthreads();
    }
}

// ---------------------------------------------------------------------------
extern "C" void kernel_launch(void* const* d_in, const int* in_sizes, int n_in,
                              void* d_out, int out_size, void* d_ws, size_t ws_size,
                              hipStream_t stream)
{
    const float* x      = (const float*)d_in[0];
    const float* prompt = (const float*)d_in[1];
    const float* Wx     = (const float*)d_in[2];
    const float* Wdt    = (const float*)d_in[3];
    const float* bdt    = (const float*)d_in[4];
    const float* A_log  = (const float*)d_in[5];
    const float* Dskip  = (const float*)d_in[6];
    float* out = (float*)d_out;                  // holds dts between mm2 and scan3
    char* ws = (char*)d_ws;
    size_t off = 0;
    unsigned* scales       = (unsigned*)(ws + off);        off += 256;
    unsigned short* Wxq    = (unsigned short*)(ws + off);  off += (size_t)ODIM*DMODEL*2;
    unsigned short* Wdtq   = (unsigned short*)(ws + off);  off += (size_t)DMODEL*DTR*2;
    float* a2              = (float*)(ws + off);           off += (size_t)DMODEL*DST*4;
    float* Dq              = (float*)(ws + off);           off += (size_t)DMODEL*4;
    float* xbc             = (float*)(ws + off);           off += (size_t)MROWS*32*4;
    unsigned short* xdblbf = (unsigned short*)(ws + off);  off += (size_t)MROWS*DTR*2;
    // union region: part (4*MROWS*ODIM*4 = 21 MB, dead after k_red1)
    //               overlaps Aprod+hfin (2 x 16.8 MB, written by k_scan1)
    float* part            = (float*)(ws + off);
    float* Aprod           = (float*)(ws + off);           off += (size_t)BSZ*CH*DMODEL*DST*4;
    float* hfin            = (float*)(ws + off);           off += (size_t)BSZ*CH*DMODEL*DST*4;

    hipMemsetAsync(scales, 0, 256, stream);
    hipLaunchKernelGGL(k_prep, dim3(PREP_BLOCKS), dim3(256), 0, stream,
                       Wx, Wdt, A_log, Dskip, Wxq, Wdtq, a2, Dq);
    hipLaunchKernelGGL(k_mm1, dim3((MROWS/16)*4), dim3(64), 0, stream,
                       x, Wxq, part, scales);
    hipLaunchKernelGGL(k_red1, dim3(MROWS*ODIM/2560), dim3(256), 0, stream,
                       part, prompt, xdblbf, xbc, scales);
    hipLaunchKernelGGL(k_mm2, dim3((MROWS/64)*(DMODEL/128)), dim3(256), 0, stream,
                       xdblbf, Wdtq, bdt, out, scales);
    hipLaunchKernelGGL(k_scan1, dim3(BSZ*8*CH), dim3(256), 0, stream,
                       out, x, xbc, a2, scales, Aprod, hfin);
    hipLaunchKernelGGL(k_mid, dim3(BSZ*DMODEL*DST/256), dim3(256), 0, stream,
                       Aprod, hfin);
    hipLaunchKernelGGL(k_scan3, dim3(BSZ*8*CH), dim3(256), 0, stream,
                       out, x, xbc, a2, Dq, scales, Aprod);
}

// Round 3
// 300.160 us; speedup vs baseline: 1.9551x; 1.8044x over previous
//
#include <hip/hip_runtime.h>
#include <hip/hip_bf16.h>

#define BSZ    2
#define LSEQ   4096
#define DMODEL 2048
#define DTR    128
#define DST    16
#define ODIM   160            // DTR + 2*DST
#define MROWS  (BSZ*LSEQ)     // 8192
#define CH     64             // chunks along L
#define TT     (LSEQ/CH)      // 64 steps per chunk
#define LOG2E  1.44269504088896340736f
#define LN2    0.69314718055994530942f

typedef short  short8  __attribute__((ext_vector_type(8)));
typedef float  floatx4 __attribute__((ext_vector_type(4)));

__device__ __forceinline__ unsigned short f2bf(float f) {
    unsigned u = __float_as_uint(f);
    u += 0x7fffu + ((u >> 16) & 1u);      // round-to-nearest-even
    return (unsigned short)(u >> 16);
}
__device__ __forceinline__ float quantv(float x, float s, float inv_s) {
    float q = rintf(x * inv_s);
    q = fminf(fmaxf(q, -128.0f), 127.0f);
    return q * s;
}
__device__ __forceinline__ float softplus_fast(float v) {
    float t = __builtin_amdgcn_exp2f(-fabsf(v) * LOG2E);
    return fmaxf(v, 0.0f) + LN2 * __log2f(1.0f + t);
}
__device__ __forceinline__ float scale_from_bits(unsigned bits) {
    return fmaxf(__uint_as_float(bits) * (1.0f/127.0f), 1e-8f);
}
// packed MFMA-fragment offset for row-major [R x K] matrix, 16x16x32 frags:
// lane = (r&15) + 16*((k&31)>>3), elem = k&7  -> consumer loads lane*8 contiguous
__device__ __forceinline__ int pidx(int r, int k, int K) {
    return (r >> 4)*(16*K) + ((k >> 5) << 9) + (((r & 15) + (((k & 31) >> 3) << 4)) << 3) + (k & 7);
}

// ---------------------------------------------------------------- prep ------
#define PB_WX  160      // block per Wx output row
#define PB_WDT 128      // block per 16-row Wdt n-tile
#define PB_A   128
#define PB_D   1
#define PREP_BLOCKS (PB_WX + PB_WDT + PB_A + PB_D)

__global__ __launch_bounds__(256) void k_prep(
    const float* __restrict__ Wx, const float* __restrict__ Wdt,
    const float* __restrict__ A_log, const float* __restrict__ Dskip,
    unsigned short* __restrict__ Wxq, unsigned short* __restrict__ Wdtq,
    float* __restrict__ a2, float* __restrict__ Dq)
{
    int bid = blockIdx.x, tid = threadIdx.x;
    __shared__ float red[256];
    if (bid < PB_WX) {                       // Wx row o: per-channel quant -> packed bf16
        int o = bid, base = o * DMODEL;
        float m = 0.0f;
        for (int i = tid; i < DMODEL; i += 256) m = fmaxf(m, fabsf(Wx[base+i]));
        red[tid] = m; __syncthreads();
        for (int s2 = 128; s2 > 0; s2 >>= 1) { if (tid < s2) red[tid] = fmaxf(red[tid], red[tid+s2]); __syncthreads(); }
        float s = fmaxf(red[0]*(1.0f/127.0f), 1e-8f), inv = 1.0f/s;
        for (int i = tid; i < DMODEL; i += 256)
            Wxq[pidx(o, i, DMODEL)] = f2bf(quantv(Wx[base+i], s, inv));
    } else if (bid < PB_WX + PB_WDT) {       // Wdt n-tile: 16 rows, 8 elems/thread
        int n = (bid - PB_WX)*16 + (tid >> 4);
        int k0 = (tid & 15)*8;
        const float* src = Wdt + (size_t)n*DTR + k0;
        float4 v0 = *reinterpret_cast<const float4*>(src);
        float4 v1 = *reinterpret_cast<const float4*>(src + 4);
        float m = fmaxf(fmaxf(fmaxf(fabsf(v0.x), fabsf(v0.y)), fmaxf(fabsf(v0.z), fabsf(v0.w))),
                        fmaxf(fmaxf(fabsf(v1.x), fabsf(v1.y)), fmaxf(fabsf(v1.z), fabsf(v1.w))));
        for (int off = 1; off < 16; off <<= 1) m = fmaxf(m, __shfl_xor(m, off, 16));
        float s = fmaxf(m*(1.0f/127.0f), 1e-8f), inv = 1.0f/s;
        short8 o8;
        o8[0]=(short)f2bf(quantv(v0.x,s,inv)); o8[1]=(short)f2bf(quantv(v0.y,s,inv));
        o8[2]=(short)f2bf(quantv(v0.z,s,inv)); o8[3]=(short)f2bf(quantv(v0.w,s,inv));
        o8[4]=(short)f2bf(quantv(v1.x,s,inv)); o8[5]=(short)f2bf(quantv(v1.y,s,inv));
        o8[6]=(short)f2bf(quantv(v1.z,s,inv)); o8[7]=(short)f2bf(quantv(v1.w,s,inv));
        *reinterpret_cast<short8*>(Wdtq + pidx(n, k0, DTR)) = o8;
    } else if (bid < PB_WX + PB_WDT + PB_A) { // A_log -> a2 = -exp(q)*log2e
        int d = (bid - PB_WX - PB_WDT)*16 + (tid >> 4);
        int n = tid & 15;
        float v = A_log[d*DST + n];
        float m = fabsf(v);
        for (int off = 1; off < 16; off <<= 1) m = fmaxf(m, __shfl_xor(m, off, 16));
        float s = fmaxf(m*(1.0f/127.0f), 1e-8f);
        float q = quantv(v, s, 1.0f/s);
        a2[d*DST + n] = -expf(q) * LOG2E;
    } else {                                  // Dskip per-tensor quant
        float m = 0.0f;
        for (int i = tid; i < DMODEL; i += 256) m = fmaxf(m, fabsf(Dskip[i]));
        red[tid] = m; __syncthreads();
        for (int s2 = 128; s2 > 0; s2 >>= 1) { if (tid < s2) red[tid] = fmaxf(red[tid], red[tid+s2]); __syncthreads(); }
        float s = fmaxf(red[0]*(1.0f/127.0f), 1e-8f), inv = 1.0f/s;
        for (int i = tid; i < DMODEL; i += 256) Dq[i] = quantv(Dskip[i], s, inv);
    }
}

// ------ GEMM1 fused: 4 waves = 4 K-chunks of one 16-row tile, LDS-reduced ---
// writes packed bf16 dt-cols + compact B/C cols + maxes; no partials buffer
__global__ __launch_bounds__(256) void k_mm1(
    const float* __restrict__ x, const unsigned short* __restrict__ Wxq,
    const float* __restrict__ prompt,
    unsigned short* __restrict__ xdblbf, float* __restrict__ xbc,
    unsigned* __restrict__ scales)
{
    int tid = threadIdx.x, w = tid >> 6, lane = tid & 63;
    int mrow = lane & 15, quad = lane >> 4;
    int mt = blockIdx.x, m0 = mt*16, k0 = w*512;
    floatx4 acc[10] = {};
    float xmax = 0.0f;
    const float* arow = x + (size_t)(m0 + mrow)*DMODEL + k0 + quad*8;
    for (int kk = 0; kk < 512; kk += 32) {
        const float4* ap = reinterpret_cast<const float4*>(arow + kk);
        float4 a0 = ap[0], a1 = ap[1];
        xmax = fmaxf(xmax, fmaxf(fmaxf(fabsf(a0.x), fabsf(a0.y)), fmaxf(fabsf(a0.z), fabsf(a0.w))));
        xmax = fmaxf(xmax, fmaxf(fmaxf(fabsf(a1.x), fabsf(a1.y)), fmaxf(fabsf(a1.z), fabsf(a1.w))));
        short8 af;
        af[0]=(short)f2bf(a0.x); af[1]=(short)f2bf(a0.y); af[2]=(short)f2bf(a0.z); af[3]=(short)f2bf(a0.w);
        af[4]=(short)f2bf(a1.x); af[5]=(short)f2bf(a1.y); af[6]=(short)f2bf(a1.z); af[7]=(short)f2bf(a1.w);
        int kcidx = (k0 + kk) >> 5;
        #pragma unroll
        for (int j = 0; j < 10; ++j) {
            short8 bf = *reinterpret_cast<const short8*>(Wxq + j*16*DMODEL + kcidx*512 + lane*8);
            acc[j] = __builtin_amdgcn_mfma_f32_16x16x32_bf16(af, bf, acc[j], 0, 0, 0);
        }
    }
    for (int off = 32; off; off >>= 1) xmax = fmaxf(xmax, __shfl_xor(xmax, off, 64));
    __shared__ float red[4*2560];
    __shared__ float redB[256], redC[256];
    __shared__ float wred[4];
    if (lane == 0) wred[w] = xmax;
    #pragma unroll
    for (int j = 0; j < 10; ++j) {
        float4 v = make_float4(acc[j][0], acc[j][1], acc[j][2], acc[j][3]);
        *reinterpret_cast<float4*>(&red[w*2560 + (j*16 + mrow)*16 + quad*4]) = v;
    }
    __syncthreads();
    float bmax = 0.0f, cmax = 0.0f;
    #pragma unroll
    for (int j = 0; j < 10; ++j) {
        int e = j*256 + tid;
        float v = red[e] + red[2560+e] + red[5120+e] + red[7680+e];
        int col = e >> 4, rowin = e & 15, row = m0 + rowin;
        if (col < DTR) {
            xdblbf[mt*16*DTR + ((col>>5)<<9) + ((rowin + (((col&31)>>3)<<4))<<3) + (col&7)] = f2bf(v);
        } else if (col < DTR + DST) {
            bmax = fmaxf(bmax, fabsf(v));
            xbc[(size_t)row*32 + (col - DTR)] = v;
        } else {
            v += prompt[(size_t)row*DST + (col - DTR - DST)];
            cmax = fmaxf(cmax, fabsf(v));
            xbc[(size_t)row*32 + 16 + (col - DTR - DST)] = v;
        }
    }
    redB[tid] = bmax; redC[tid] = cmax; __syncthreads();
    for (int s2 = 128; s2 > 0; s2 >>= 1) {
        if (tid < s2) { redB[tid] = fmaxf(redB[tid], redB[tid+s2]); redC[tid] = fmaxf(redC[tid], redC[tid+s2]); }
        __syncthreads();
    }
    if (tid == 0) {
        atomicMax(&scales[0], __float_as_uint(fmaxf(fmaxf(wred[0], wred[1]), fmaxf(wred[2], wred[3]))));
        atomicMax(&scales[1], __float_as_uint(redB[0]));
        atomicMax(&scales[2], __float_as_uint(redC[0]));
    }
}

// ---------------- GEMM2: dts = xdbl[:, :128] @ Wdt^T + bdt (packed operands) -
__global__ __launch_bounds__(256) void k_mm2(
    const unsigned short* __restrict__ Ap, const unsigned short* __restrict__ Bp,
    const float* __restrict__ bdt, float* __restrict__ dts, unsigned* __restrict__ scales)
{
    int tid = threadIdx.x, w = tid >> 6, lane = tid & 63;
    int mrow = lane & 15, quad = lane >> 4;
    int mt = blockIdx.x >> 4, nt = blockIdx.x & 15;
    int mtile = mt*4 + w, m0 = mtile*16, n0 = nt*128;
    short8 afr[4];
    const unsigned short* ab = Ap + (size_t)mtile*16*DTR + lane*8;
    #pragma unroll
    for (int kc = 0; kc < 4; ++kc) afr[kc] = *reinterpret_cast<const short8*>(ab + (kc<<9));
    floatx4 acc[8] = {};
    #pragma unroll
    for (int j = 0; j < 8; ++j) {
        const unsigned short* bb = Bp + (size_t)(n0/16 + j)*16*DTR + lane*8;
        #pragma unroll
        for (int kc = 0; kc < 4; ++kc) {
            short8 bf = *reinterpret_cast<const short8*>(bb + (kc<<9));
            acc[j] = __builtin_amdgcn_mfma_f32_16x16x32_bf16(afr[kc], bf, acc[j], 0, 0, 0);
        }
    }
    float dmax = 0.0f;
    #pragma unroll
    for (int j = 0; j < 8; ++j) {
        int col = n0 + j*16 + mrow;
        float bv = bdt[col];
        #pragma unroll
        for (int r = 0; r < 4; ++r) {
            int row = m0 + quad*4 + r;
            float v = acc[j][r] + bv;
            dmax = fmaxf(dmax, fabsf(v));
            dts[(size_t)row*DMODEL + col] = v;
        }
    }
    for (int off = 32; off; off >>= 1) dmax = fmaxf(dmax, __shfl_xor(dmax, off, 64));
    __shared__ float wd[4];
    if (lane == 0) wd[w] = dmax;
    __syncthreads();
    if (tid == 0)
        atomicMax(&scales[3], __float_as_uint(fmaxf(fmaxf(wd[0], wd[1]), fmaxf(wd[2], wd[3]))));
}

// ------------------------------------------- scan phase 1: chunk aggregates -
__global__ __launch_bounds__(256) void k_scan1(
    const float* __restrict__ dts, const float* __restrict__ x,
    const float* __restrict__ xbc, const float* __restrict__ a2,
    const unsigned* __restrict__ scales,
    float* __restrict__ Aprod, float* __restrict__ hfin)
{
    int bid = blockIdx.x, tid = threadIdx.x;
    int b = bid >> 9, rem = bid & 511, dblk = rem >> 6, ch = rem & 63;
    int d = dblk*256 + tid, t0 = ch*TT;
    float s_u  = scale_from_bits(scales[0]), inv_su  = 1.0f/s_u;
    float s_B  = scale_from_bits(scales[1]), inv_sB  = 1.0f/s_B;
    float s_dt = scale_from_bits(scales[3]), inv_sdt = 1.0f/s_dt;
    float a2r[16];
    {
        const float4* ap = reinterpret_cast<const float4*>(a2 + (size_t)d*DST);
        float4 v0 = ap[0], v1 = ap[1], v2 = ap[2], v3 = ap[3];
        a2r[0]=v0.x; a2r[1]=v0.y; a2r[2]=v0.z; a2r[3]=v0.w;
        a2r[4]=v1.x; a2r[5]=v1.y; a2r[6]=v1.z; a2r[7]=v1.w;
        a2r[8]=v2.x; a2r[9]=v2.y; a2r[10]=v2.z; a2r[11]=v2.w;
        a2r[12]=v3.x; a2r[13]=v3.y; a2r[14]=v3.z; a2r[15]=v3.w;
    }
    float h[16];
    #pragma unroll
    for (int n = 0; n < 16; ++n) h[n] = 0.0f;
    float sdt = 0.0f;
    __shared__ __align__(16) float Bq_p[8*16];
    for (int sub = 0; sub < TT/8; ++sub) {
        int tbase = t0 + sub*8;
        if (tid < 128) {
            int tb = tid >> 4, n = tid & 15;
            Bq_p[tid] = quantv(xbc[(size_t)(b*LSEQ + tbase + tb)*32 + n], s_B, inv_sB);
        }
        float dtr[8], ur[8];
        const float* pD = dts + (size_t)(b*LSEQ + tbase)*DMODEL + d;
        const float* pX = x   + (size_t)(b*LSEQ + tbase)*DMODEL + d;
        #pragma unroll
        for (int r = 0; r < 8; ++r) { dtr[r] = pD[(size_t)r*DMODEL]; ur[r] = pX[(size_t)r*DMODEL]; }
        __syncthreads();
        #pragma unroll
        for (int r = 0; r < 8; ++r) {
            float dtq = quantv(dtr[r], s_dt, inv_sdt);
            float dtv = softplus_fast(dtq);
            float uq  = quantv(ur[r], s_u, inv_su);
            float dtu = dtv * uq;
            sdt += dtv;
            const float4* bq4 = reinterpret_cast<const float4*>(&Bq_p[r*16]);
            float4 b0 = bq4[0], b1 = bq4[1], b2 = bq4[2], b3 = bq4[3];
            float bq[16] = { b0.x,b0.y,b0.z,b0.w, b1.x,b1.y,b1.z,b1.w,
                             b2.x,b2.y,b2.z,b2.w, b3.x,b3.y,b3.z,b3.w };
            #pragma unroll
            for (int n = 0; n < 16; ++n) {
                float dA = __builtin_amdgcn_exp2f(a2r[n]*dtv);
                h[n] = fmaf(dA, h[n], dtu*bq[n]);
            }
        }
        __syncthreads();
    }
    size_t ob = ((size_t)((b*CH + ch)*DMODEL + d))*DST;
    #pragma unroll
    for (int i = 0; i < 4; ++i) {
        float4 av = make_float4(__builtin_amdgcn_exp2f(a2r[4*i+0]*sdt),
                                __builtin_amdgcn_exp2f(a2r[4*i+1]*sdt),
                                __builtin_amdgcn_exp2f(a2r[4*i+2]*sdt),
                                __builtin_amdgcn_exp2f(a2r[4*i+3]*sdt));
        float4 hv = make_float4(h[4*i+0], h[4*i+1], h[4*i+2], h[4*i+3]);
        *reinterpret_cast<float4*>(Aprod + ob + 4*i) = av;
        *reinterpret_cast<float4*>(hfin  + ob + 4*i) = hv;
    }
}

// ------------------------- scan phase 2: across-chunk recurrence (in-place) -
__global__ __launch_bounds__(256) void k_mid(
    float* __restrict__ Aprod, const float* __restrict__ hfin)
{
    int f = blockIdx.x*256 + threadIdx.x;      // 65536 = B*DMODEL*DST
    int b = f >> 15, dn = f & 32767;
    size_t base = (size_t)b*CH*32768 + dn;
    float h = 0.0f;
    #pragma unroll 4
    for (int ch = 0; ch < CH; ++ch) {
        size_t o = base + (size_t)ch*32768;
        float a = Aprod[o], hf = hfin[o];
        Aprod[o] = h;                          // exclusive prefix -> h_init
        h = fmaf(a, h, hf);
    }
}

// --------------------- scan phase 3: replay with h_init, emit y + u_q*D_q ---
__global__ __launch_bounds__(256) void k_scan3(
    float* __restrict__ io /* dts in, y out */,
    const float* __restrict__ x, const float* __restrict__ xbc,
    const float* __restrict__ a2, const float* __restrict__ Dq,
    const unsigned* __restrict__ scales, const float* __restrict__ hinit)
{
    int bid = blockIdx.x, tid = threadIdx.x;
    int b = bid >> 9, rem = bid & 511, dblk = rem >> 6, ch = rem & 63;
    int d = dblk*256 + tid, t0 = ch*TT;
    float s_u  = scale_from_bits(scales[0]), inv_su  = 1.0f/s_u;
    float s_B  = scale_from_bits(scales[1]), inv_sB  = 1.0f/s_B;
    float s_C  = scale_from_bits(scales[2]), inv_sC  = 1.0f/s_C;
    float s_dt = scale_from_bits(scales[3]), inv_sdt = 1.0f/s_dt;
    float dqd = Dq[d];
    float a2r[16];
    {
        const float4* ap = reinterpret_cast<const float4*>(a2 + (size_t)d*DST);
        float4 v0 = ap[0], v1 = ap[1], v2 = ap[2], v3 = ap[3];
        a2r[0]=v0.x; a2r[1]=v0.y; a2r[2]=v0.z; a2r[3]=v0.w;
        a2r[4]=v1.x; a2r[5]=v1.y; a2r[6]=v1.z; a2r[7]=v1.w;
        a2r[8]=v2.x; a2r[9]=v2.y; a2r[10]=v2.z; a2r[11]=v2.w;
        a2r[12]=v3.x; a2r[13]=v3.y; a2r[14]=v3.z; a2r[15]=v3.w;
    }
    size_t ob = ((size_t)((b*CH + ch)*DMODEL + d))*DST;
    float h[16];
    #pragma unroll
    for (int i = 0; i < 4; ++i) {
        float4 hv = *reinterpret_cast<const float4*>(hinit + ob + 4*i);
        h[4*i+0]=hv.x; h[4*i+1]=hv.y; h[4*i+2]=hv.z; h[4*i+3]=hv.w;
    }
    __shared__ __align__(16) float Bq_p[8*16];
    __shared__ __align__(16) float Cq_p[8*16];
    for (int sub = 0; sub < TT/8; ++sub) {
        int tbase = t0 + sub*8;
        if (tid < 128) {
            int tb = tid >> 4, n = tid & 15;
            size_t pidx2 = (size_t)(b*LSEQ + tbase + tb)*32;
            Bq_p[tid] = quantv(xbc[pidx2 + n],      s_B, inv_sB);
            Cq_p[tid] = quantv(xbc[pidx2 + 16 + n], s_C, inv_sC);
        }
        float dtr[8], ur[8];
        float* pD = io + (size_t)(b*LSEQ + tbase)*DMODEL + d;
        const float* pX = x + (size_t)(b*LSEQ + tbase)*DMODEL + d;
        #pragma unroll
        for (int r = 0; r < 8; ++r) { dtr[r] = pD[(size_t)r*DMODEL]; ur[r] = pX[(size_t)r*DMODEL]; }
        __syncthreads();
        #pragma unroll
        for (int r = 0; r < 8; ++r) {
            float dtq = quantv(dtr[r], s_dt, inv_sdt);
            float dtv = softplus_fast(dtq);
            float uq  = quantv(ur[r], s_u, inv_su);
            float dtu = dtv * uq;
            const float4* bq4 = reinterpret_cast<const float4*>(&Bq_p[r*16]);
            const float4* cq4 = reinterpret_cast<const float4*>(&Cq_p[r*16]);
            float4 b0 = bq4[0], b1 = bq4[1], b2 = bq4[2], b3 = bq4[3];
            float4 c0 = cq4[0], c1 = cq4[1], c2 = cq4[2], c3 = cq4[3];
            float bq[16] = { b0.x,b0.y,b0.z,b0.w, b1.x,b1.y,b1.z,b1.w,
                             b2.x,b2.y,b2.z,b2.w, b3.x,b3.y,b3.z,b3.w };
            float cq[16] = { c0.x,c0.y,c0.z,c0.w, c1.x,c1.y,c1.z,c1.w,
                             c2.x,c2.y,c2.z,c2.w, c3.x,c3.y,c3.z,c3.w };
            float y = 0.0f;
            #pragma unroll
            for (int n = 0; n < 16; ++n) {
                float dA = __builtin_amdgcn_exp2f(a2r[n]*dtv);
                h[n] = fmaf(dA, h[n], dtu*bq[n]);
                y = fmaf(h[n], cq[n], y);
            }
            pD[(size_t)r*DMODEL] = y + uq * dqd;
        }
        __syncthreads();
    }
}

// ---------------------------------------------------------------------------
extern "C" void kernel_launch(void* const* d_in, const int* in_sizes, int n_in,
                              void* d_out, int out_size, void* d_ws, size_t ws_size,
                              hipStream_t stream)
{
    const float* x      = (const float*)d_in[0];
    const float* prompt = (const float*)d_in[1];
    const float* Wx     = (const float*)d_in[2];
    const float* Wdt    = (const float*)d_in[3];
    const float* bdt    = (const float*)d_in[4];
    const float* A_log  = (const float*)d_in[5];
    const float* Dskip  = (const float*)d_in[6];
    float* out = (float*)d_out;                  // holds dts between mm2 and scan3
    char* ws = (char*)d_ws;
    size_t off = 0;
    unsigned* scales       = (unsigned*)(ws + off);        off += 256;
    unsigned short* Wxq    = (unsigned short*)(ws + off);  off += (size_t)ODIM*DMODEL*2;
    unsigned short* Wdtq   = (unsigned short*)(ws + off);  off += (size_t)DMODEL*DTR*2;
    float* a2              = (float*)(ws + off);           off += (size_t)DMODEL*DST*4;
    float* Dq              = (float*)(ws + off);           off += (size_t)DMODEL*4;
    float* xbc             = (float*)(ws + off);           off += (size_t)MROWS*32*4;
    unsigned short* xdblbf = (unsigned short*)(ws + off);  off += (size_t)MROWS*DTR*2;
    float* Aprod           = (float*)(ws + off);           off += (size_t)BSZ*CH*DMODEL*DST*4;
    float* hfin            = (float*)(ws + off);           off += (size_t)BSZ*CH*DMODEL*DST*4;

    hipMemsetAsync(scales, 0, 256, stream);
    hipLaunchKernelGGL(k_prep, dim3(PREP_BLOCKS), dim3(256), 0, stream,
                       Wx, Wdt, A_log, Dskip, Wxq, Wdtq, a2, Dq);
    hipLaunchKernelGGL(k_mm1, dim3(MROWS/16), dim3(256), 0, stream,
                       x, Wxq, prompt, xdblbf, xbc, scales);
    hipLaunchKernelGGL(k_mm2, dim3((MROWS/64)*(DMODEL/128)), dim3(256), 0, stream,
                       xdblbf, Wdtq, bdt, out, scales);
    hipLaunchKernelGGL(k_scan1, dim3(BSZ*8*CH), dim3(256), 0, stream,
                       out, x, xbc, a2, scales, Aprod, hfin);
    hipLaunchKernelGGL(k_mid, dim3(BSZ*DMODEL*DST/256), dim3(256), 0, stream,
                       Aprod, hfin);
    hipLaunchKernelGGL(k_scan3, dim3(BSZ*8*CH), dim3(256), 0, stream,
                       out, x, xbc, a2, Dq, scales, Aprod);
}